// Round 1
// baseline (21321.184 us; speedup 1.0000x reference)
//
#include <hip/hip_runtime.h>

// ---------------------------------------------------------------------------
// BlockLSTM forward, MI355X (gfx950).
//   T=512, B=64, I=U=512.  out = [h_seq (T,B,U) | final_cs (B,U) | final_h (B,U)] fp32
//
// ws layout (needs ~164.1 MB):
//   [0,   4MB)   wT   bf16 [2048][1024]   (wT[n][k] = w[k][n])
//   [4, 132MB)   zx   bf16 [T*B][2048]    (x@wx + b)
//   [132,164MB)  hbf  bf16 [T*B][512]     (h in bf16, producer->consumer)
//   [164MB, +64KB) flags u32 [T][4][8]    (per-(t,bg) split counters)
// ---------------------------------------------------------------------------

#define T_STEPS 512
#define NB 64
#define NU 512
#define NI 512
#define KTOT 1024
#define ZCOLS 2048
#define HSEQ_ELEMS (T_STEPS * NB * NU)

typedef float    floatx4  __attribute__((ext_vector_type(4)));
typedef __bf16   bf16x8   __attribute__((ext_vector_type(8)));
typedef unsigned short ushortx8 __attribute__((ext_vector_type(8)));

static __device__ __forceinline__ unsigned short f2bf(float f) {
  unsigned int u = __builtin_bit_cast(unsigned int, f);
  u += 0x7fffu + ((u >> 16) & 1u);           // RNE
  return (unsigned short)(u >> 16);
}
static __device__ __forceinline__ float bf2f(unsigned short h) {
  unsigned int u = ((unsigned int)h) << 16;
  return __builtin_bit_cast(float, u);
}
static __device__ __forceinline__ float sigmoidf_(float x) {
  return 1.0f / (1.0f + __expf(-x));
}
static __device__ __forceinline__ bf16x8 ldfrag(const unsigned short* p) {
  ushortx8 v = *reinterpret_cast<const ushortx8*>(p);
  return __builtin_bit_cast(bf16x8, v);
}
static __device__ __forceinline__ unsigned long long pack4bf(float a, float b,
                                                            float c, float d) {
  return (unsigned long long)f2bf(a) | ((unsigned long long)f2bf(b) << 16) |
         ((unsigned long long)f2bf(c) << 32) | ((unsigned long long)f2bf(d) << 48);
}

// ---------------------------------------------------------------------------
// Kernel 1: wT[n][k] = bf16(w[k][n]);  w: [1024][2048] fp32, wT: [2048][1024] bf16
// ---------------------------------------------------------------------------
__global__ __launch_bounds__(256) void transpose_w_kernel(
    const float* __restrict__ w, unsigned short* __restrict__ wT) {
  __shared__ float tile[32][33];
  const int n0 = blockIdx.x * 32;   // 64 tiles over 2048
  const int k0 = blockIdx.y * 32;   // 32 tiles over 1024
  const int tx = threadIdx.x & 31, ty = threadIdx.x >> 5;  // ty in [0,8)
#pragma unroll
  for (int r = 0; r < 4; ++r) {
    const int k = ty + r * 8;
    tile[k][tx] = w[(k0 + k) * ZCOLS + n0 + tx];
  }
  __syncthreads();
#pragma unroll
  for (int r = 0; r < 4; ++r) {
    const int n = ty + r * 8;
    wT[(size_t)(n0 + n) * KTOT + k0 + tx] = f2bf(tile[tx][n]);
  }
}

// ---------------------------------------------------------------------------
// Kernel 2: zx[m][n] = bf16( sum_k x[m][k]*w[k][n] + bias[n] ),  m<32768, n<2048, K=512
// 128x128 tile, 256 thr = 4 waves (2x2), each wave 4x4 of 16x16x32 MFMA.
// ---------------------------------------------------------------------------
__global__ __launch_bounds__(256) void gemm_zx_kernel(
    const float* __restrict__ x, const unsigned short* __restrict__ wT,
    const float* __restrict__ bias, unsigned short* __restrict__ zx) {
  __shared__ __align__(16) unsigned short As[128][32];  // [m][k] bf16
  __shared__ __align__(16) unsigned short Bs[128][32];  // [n][k] bf16
  const int m0 = blockIdx.y * 128;
  const int n0 = blockIdx.x * 128;
  const int tid = threadIdx.x;
  const int wid = tid >> 6, lane = tid & 63;
  const int quad = lane >> 4, nl = lane & 15;
  const int wm = (wid & 1) * 64, wn = (wid >> 1) * 64;
  const int srow = tid >> 3;          // [0,32)
  const int skk = (tid & 7) * 4;      // [0,32) step 4

  floatx4 acc[4][4] = {};

  for (int kt = 0; kt < 16; ++kt) {
    const int k0 = kt * 32;
    __syncthreads();
#pragma unroll
    for (int r = 0; r < 4; ++r) {
      const int row = r * 32 + srow;
      const float4 v =
          *reinterpret_cast<const float4*>(&x[(size_t)(m0 + row) * NI + k0 + skk]);
      *reinterpret_cast<unsigned long long*>(&As[row][skk]) =
          pack4bf(v.x, v.y, v.z, v.w);
      *reinterpret_cast<unsigned long long*>(&Bs[row][skk]) =
          *reinterpret_cast<const unsigned long long*>(
              &wT[(size_t)(n0 + row) * KTOT + k0 + skk]);
    }
    __syncthreads();
    bf16x8 af[4], bfr[4];
#pragma unroll
    for (int i = 0; i < 4; ++i) {
      af[i] = ldfrag(&As[wm + i * 16 + nl][quad * 8]);
      bfr[i] = ldfrag(&Bs[wn + i * 16 + nl][quad * 8]);
    }
#pragma unroll
    for (int i = 0; i < 4; ++i)
#pragma unroll
      for (int j = 0; j < 4; ++j)
        acc[i][j] =
            __builtin_amdgcn_mfma_f32_16x16x32_bf16(af[i], bfr[j], acc[i][j], 0, 0, 0);
  }

  float bv[4];
#pragma unroll
  for (int j = 0; j < 4; ++j) bv[j] = bias[n0 + wn + j * 16 + nl];
#pragma unroll
  for (int i = 0; i < 4; ++i)
#pragma unroll
    for (int j = 0; j < 4; ++j)
#pragma unroll
      for (int r = 0; r < 4; ++r) {
        const int row = m0 + wm + i * 16 + quad * 4 + r;
        const int col = n0 + wn + j * 16 + nl;
        zx[(size_t)row * ZCOLS + col] = f2bf(acc[i][j][r] + bv[j]);
      }
}

// ---------------------------------------------------------------------------
// Kernel 3: persistent recurrence. 256 blocks x 128 thr (2 waves).
// wave owns (bg = blockIdx&3 -> rows bg*16..+16, us -> units us*4..+4, 16 z-cols).
// Per step: C(init=zx) += h_prev[16x512] @ wh[512x16] via 16 MFMA; gates; h out.
// ---------------------------------------------------------------------------
__global__ __launch_bounds__(128) void lstm_rec_kernel(
    const unsigned short* __restrict__ zx, const unsigned short* __restrict__ wT,
    const float* __restrict__ cs0, const float* __restrict__ h0,
    float* __restrict__ out, unsigned short* __restrict__ hbf,
    unsigned int* flags) {
  const int bg = blockIdx.x & 3;
  const int wave = threadIdx.x >> 6;
  const int lane = threadIdx.x & 63;
  const int us = (blockIdx.x >> 2) * 2 + wave;  // [0,128)
  const int quad = lane >> 4, nl = lane & 15;
  const int g = nl >> 2, ul = nl & 3;
  const int gcol = g * 512 + us * 4 + ul;       // z column for this lane (B/n side)

  // --- static B fragments: wh[:, gcol] in registers for the whole kernel ---
  bf16x8 bfrag[16];
#pragma unroll
  for (int kk = 0; kk < 16; ++kk)
    bfrag[kk] = ldfrag(&wT[(size_t)gcol * KTOT + 512 + kk * 32 + quad * 8]);

  // --- gate-lane state ---
  const int grow = lane >> 2, gul = lane & 3;
  const int bG = bg * 16 + grow;      // global batch row
  const int uG = us * 4 + gul;        // global unit
  float cs = cs0[bG * NU + uG];

  __shared__ float zsh[2][16][17];
  const int myflag = us & 7;

  for (int t = 0; t < T_STEPS; ++t) {
    // zx prefetch (C init), rows quad*4+r, col gcol
    unsigned short zr[4];
#pragma unroll
    for (int r = 0; r < 4; ++r)
      zr[r] = zx[(size_t)(t * NB + bg * 16 + quad * 4 + r) * ZCOLS + gcol];

    // wait for h[t-1] from all 128 us-slices of this bg
    if (t > 0) {
      unsigned int* fb = flags + ((t - 1) * 4 + bg) * 8;
      int guard = 0;
      while (guard++ < (1 << 24)) {
        unsigned s = 0;
#pragma unroll
        for (int i = 0; i < 8; ++i)
          s += __hip_atomic_load(fb + i, __ATOMIC_RELAXED, __HIP_MEMORY_SCOPE_AGENT);
        if (s >= 128) break;
        __builtin_amdgcn_s_sleep(2);
      }
      __threadfence();  // acquire: make producers' hbf stores visible
    }

    // A fragments: h_prev rows bg*16+nl, bf16
    bf16x8 af[16];
    if (t == 0) {
      const float* hp = &h0[(bg * 16 + nl) * NU];
#pragma unroll
      for (int kk = 0; kk < 16; ++kk) {
        ushortx8 tv;
#pragma unroll
        for (int j = 0; j < 8; ++j) tv[j] = f2bf(hp[kk * 32 + quad * 8 + j]);
        af[kk] = __builtin_bit_cast(bf16x8, tv);
      }
    } else {
      const unsigned short* hp = &hbf[(size_t)((t - 1) * NB + bg * 16 + nl) * NU];
#pragma unroll
      for (int kk = 0; kk < 16; ++kk) af[kk] = ldfrag(&hp[kk * 32 + quad * 8]);
    }

    // z = zx + h_prev @ wh   (two acc chains to halve MFMA dep latency)
    floatx4 c0, c1;
#pragma unroll
    for (int r = 0; r < 4; ++r) { c0[r] = bf2f(zr[r]); c1[r] = 0.0f; }
#pragma unroll
    for (int kk = 0; kk < 16; kk += 2) {
      c0 = __builtin_amdgcn_mfma_f32_16x16x32_bf16(af[kk], bfrag[kk], c0, 0, 0, 0);
      c1 = __builtin_amdgcn_mfma_f32_16x16x32_bf16(af[kk + 1], bfrag[kk + 1], c1, 0, 0, 0);
    }

    __syncthreads();
#pragma unroll
    for (int r = 0; r < 4; ++r) zsh[wave][quad * 4 + r][nl] = c0[r] + c1[r];
    __syncthreads();

    // gates: cols 0..3=i, 4..7=ci, 8..11=f, 12..15=o (col = g*4 + u_local)
    const float zi = zsh[wave][grow][gul];
    const float zci = zsh[wave][grow][4 + gul];
    const float zf = zsh[wave][grow][8 + gul];
    const float zo = zsh[wave][grow][12 + gul];
    const float iv = sigmoidf_(zi);
    const float fv = sigmoidf_(zf + 1.0f);  // forget_bias
    const float civ = tanhf(zci);
    const float ov = sigmoidf_(zo);
    cs = civ * iv + cs * fv;
    const float h = tanhf(cs) * ov;

    const int oidx = (t * NB + bG) * NU + uG;
    out[oidx] = h;
    hbf[oidx] = f2bf(h);
    if (t == T_STEPS - 1) {
      out[HSEQ_ELEMS + bG * NU + uG] = cs;
      out[HSEQ_ELEMS + NB * NU + bG * NU + uG] = h;
    }

    __threadfence();  // release: drain h stores before signaling
    if (lane == 0) atomicAdd(&flags[(t * 4 + bg) * 8 + myflag], 1u);
  }
}

// ---------------------------------------------------------------------------
extern "C" void kernel_launch(void* const* d_in, const int* in_sizes, int n_in,
                              void* d_out, int out_size, void* d_ws, size_t ws_size,
                              hipStream_t stream) {
  const float* x = (const float*)d_in[0];
  const float* cs0 = (const float*)d_in[1];
  const float* h0 = (const float*)d_in[2];
  const float* w = (const float*)d_in[3];
  const float* bias = (const float*)d_in[4];
  float* out = (float*)d_out;

  char* ws = (char*)d_ws;
  unsigned short* wT = (unsigned short*)(ws);
  unsigned short* zx = (unsigned short*)(ws + (size_t)(4 << 20));
  unsigned short* hbf = (unsigned short*)(ws + (size_t)(132 << 20));
  unsigned int* flags = (unsigned int*)(ws + (size_t)(164 << 20));

  hipMemsetAsync(flags, 0, T_STEPS * 4 * 8 * sizeof(unsigned int), stream);
  transpose_w_kernel<<<dim3(64, 32), 256, 0, stream>>>(w, wT);
  gemm_zx_kernel<<<dim3(16, 256), 256, 0, stream>>>(x, wT, bias, zx);
  lstm_rec_kernel<<<dim3(256), 128, 0, stream>>>(zx, wT, cs0, h0, out, hbf, flags);
}

// Round 2
// 10670.303 us; speedup vs baseline: 1.9982x; 1.9982x over previous
//
#include <hip/hip_runtime.h>

// ---------------------------------------------------------------------------
// BlockLSTM forward, MI355X (gfx950).  T=512, B=64, I=U=512.
// out = [h_seq (T,B,U) | final_cs (B,U) | final_h (B,U)] fp32
//
// z-columns permuted unit-major: col' = u*4 + g  (orig col = g*512 + u).
// zxp stored in MFMA 32x32 C-fragment order: [t][cb][rt][lane][reg] bf16.
//
// ws layout (~164.1 MB):
//   [0,   4MB)        wT   bf16 [2048 permuted cols][1024 k]
//   [4MB, 132MB)      zxp  bf16 [512][64][2][64][16]
//   [132MB, +32.06MB) hbf  bf16 [513 slots][64][512]  (slot t = h_{t-1})
//   [164MB+64KB, +16KB) flags u32 [512][8]
// ---------------------------------------------------------------------------

#define T_STEPS 512
#define NB 64
#define NU 512
#define NI 512
#define KTOT 1024
#define ZCOLS 2048
#define HSEQ_ELEMS (T_STEPS * NB * NU)

typedef float    floatx4   __attribute__((ext_vector_type(4)));
typedef float    floatx16  __attribute__((ext_vector_type(16)));
typedef __bf16   bf16x8    __attribute__((ext_vector_type(8)));
typedef unsigned short ushortx8 __attribute__((ext_vector_type(8)));
typedef unsigned long long ull_t;

static __device__ __forceinline__ unsigned short f2bf(float f) {
  unsigned int u = __builtin_bit_cast(unsigned int, f);
  u += 0x7fffu + ((u >> 16) & 1u);  // RNE
  return (unsigned short)(u >> 16);
}
static __device__ __forceinline__ float bf2f(unsigned short h) {
  unsigned int u = ((unsigned int)h) << 16;
  return __builtin_bit_cast(float, u);
}
static __device__ __forceinline__ float sigmoidf_(float x) {
  return 1.0f / (1.0f + __expf(-x));
}
static __device__ __forceinline__ bf16x8 ldfrag(const unsigned short* p) {
  ushortx8 v = *reinterpret_cast<const ushortx8*>(p);
  return __builtin_bit_cast(bf16x8, v);
}
static __device__ __forceinline__ ull_t pack4bf(float a, float b, float c, float d) {
  return (ull_t)f2bf(a) | ((ull_t)f2bf(b) << 16) | ((ull_t)f2bf(c) << 32) |
         ((ull_t)f2bf(d) << 48);
}
// 16B fragment load that bypasses L1/L2 (agent-coherent read from IF$).
static __device__ __forceinline__ bf16x8 ld_agent16(const unsigned short* p) {
  ull_t lo = __hip_atomic_load((const ull_t*)p, __ATOMIC_RELAXED, __HIP_MEMORY_SCOPE_AGENT);
  ull_t hi = __hip_atomic_load((const ull_t*)(p + 4), __ATOMIC_RELAXED, __HIP_MEMORY_SCOPE_AGENT);
  struct P { ull_t a, b; } s{lo, hi};
  return __builtin_bit_cast(bf16x8, s);
}

// ---------------------------------------------------------------------------
// init: zero flags, hbf slot0 = bf16(h0)
// ---------------------------------------------------------------------------
__global__ __launch_bounds__(256) void init_kernel(const float* __restrict__ h0,
                                                   unsigned short* __restrict__ hbf,
                                                   unsigned int* __restrict__ flags) {
  const int i = blockIdx.x * 256 + threadIdx.x;
  if (i < T_STEPS * 8) flags[i] = 0;
  if (i < NB * NU) hbf[i] = f2bf(h0[i]);
}

// ---------------------------------------------------------------------------
// transpose + permute: wT[(u*4+g)][k] = bf16(w[k][g*512+u])
// ---------------------------------------------------------------------------
__global__ __launch_bounds__(256) void transpose_w_kernel(
    const float* __restrict__ w, unsigned short* __restrict__ wT) {
  __shared__ float tile[32][33];
  const int u0 = blockIdx.x * 32;   // 16 tiles over 512 units
  const int k0 = blockIdx.y * 32;   // 32 tiles over 1024 k
  const int g = blockIdx.z;         // 4 gates
  const int tx = threadIdx.x & 31, ty = threadIdx.x >> 5;
#pragma unroll
  for (int r = 0; r < 4; ++r) {
    const int k = ty + r * 8;
    tile[k][tx] = w[(size_t)(k0 + k) * ZCOLS + g * 512 + u0 + tx];
  }
  __syncthreads();
#pragma unroll
  for (int r = 0; r < 4; ++r) {
    const int u = ty + r * 8;
    wT[(size_t)((u0 + u) * 4 + g) * KTOT + k0 + tx] = f2bf(tile[tx][u]);
  }
}

// ---------------------------------------------------------------------------
// gemm: zxp = (x @ wx + b) in permuted cols, stored in 32x32 C-fragment order.
// 128x128 tile, 4 waves, 4x4 of 16x16x32 MFMA.
// ---------------------------------------------------------------------------
__global__ __launch_bounds__(256) void gemm_zx_kernel(
    const float* __restrict__ x, const unsigned short* __restrict__ wT,
    const float* __restrict__ bias, unsigned short* __restrict__ zxp) {
  __shared__ __align__(16) unsigned short As[128][32];
  __shared__ __align__(16) unsigned short Bs[128][32];
  const int m0 = blockIdx.y * 128;
  const int n0 = blockIdx.x * 128;
  const int tid = threadIdx.x;
  const int wid = tid >> 6, lane = tid & 63;
  const int quad = lane >> 4, nl = lane & 15;
  const int wm = (wid & 1) * 64, wn = (wid >> 1) * 64;
  const int srow = tid >> 3;
  const int skk = (tid & 7) * 4;

  floatx4 acc[4][4] = {};

  for (int kt = 0; kt < 16; ++kt) {
    const int k0 = kt * 32;
    __syncthreads();
#pragma unroll
    for (int r = 0; r < 4; ++r) {
      const int row = r * 32 + srow;
      const float4 v =
          *reinterpret_cast<const float4*>(&x[(size_t)(m0 + row) * NI + k0 + skk]);
      *reinterpret_cast<ull_t*>(&As[row][skk]) = pack4bf(v.x, v.y, v.z, v.w);
      *reinterpret_cast<ull_t*>(&Bs[row][skk]) =
          *reinterpret_cast<const ull_t*>(&wT[(size_t)(n0 + row) * KTOT + k0 + skk]);
    }
    __syncthreads();
    bf16x8 af[4], bfr[4];
#pragma unroll
    for (int i = 0; i < 4; ++i) {
      af[i] = ldfrag(&As[wm + i * 16 + nl][quad * 8]);
      bfr[i] = ldfrag(&Bs[wn + i * 16 + nl][quad * 8]);
    }
#pragma unroll
    for (int i = 0; i < 4; ++i)
#pragma unroll
      for (int j = 0; j < 4; ++j)
        acc[i][j] =
            __builtin_amdgcn_mfma_f32_16x16x32_bf16(af[i], bfr[j], acc[i][j], 0, 0, 0);
  }

  float bv[4];
#pragma unroll
  for (int j = 0; j < 4; ++j) {
    const int colp = n0 + wn + j * 16 + nl;
    bv[j] = bias[(colp & 3) * 512 + (colp >> 2)];
  }
#pragma unroll
  for (int i = 0; i < 4; ++i) {
    const int browb = wm + i * 16 + quad * 4;  // +r -> row in [0,128)
    const int t = (m0 + browb) >> 6;
    const int rt = (browb >> 5) & 1;
    const int hi = (browb & 31) >> 3;
    const int qb = (browb >> 2) & 1;
#pragma unroll
    for (int j = 0; j < 4; ++j) {
      const int colp = n0 + wn + j * 16 + nl;
      const int cbl = colp >> 5;
      const int lanep = (colp & 31) + 32 * qb;
      const ull_t packed =
          pack4bf(acc[i][j][0] + bv[j], acc[i][j][1] + bv[j],
                  acc[i][j][2] + bv[j], acc[i][j][3] + bv[j]);
      *reinterpret_cast<ull_t*>(
          &zxp[((((size_t)t * 64 + cbl) * 2 + rt) * 64 + lanep) * 16 + hi * 4]) = packed;
    }
  }
}

// ---------------------------------------------------------------------------
// recurrence: 16 blocks x 256 thr (64 waves). Wave = 32 permuted z-cols
// (= 8 units) x all 64 batch rows. wh resident in 128 VGPRs. No fences,
// no __syncthreads; cross-block h via write-through (sc0 sc1) + flag counters.
// ---------------------------------------------------------------------------
__global__ __launch_bounds__(256) void lstm_rec_kernel(
    const unsigned short* __restrict__ zxp, const unsigned short* __restrict__ wT,
    const float* __restrict__ cs_init, float* __restrict__ out,
    unsigned short* __restrict__ hbf, unsigned int* __restrict__ flags) {
  const int wid = threadIdx.x >> 6, lane = threadIdx.x & 63;
  const int cb = blockIdx.x * 4 + wid;  // 0..63: cols [cb*32, +32) = units [cb*8, +8)
  const int rl = lane & 31, q = lane >> 5;

  // resident B fragments: wh rows (k=512..1023)
  bf16x8 Bf[32];
#pragma unroll
  for (int kt = 0; kt < 32; ++kt)
    Bf[kt] = ldfrag(&wT[(size_t)(cb * 32 + rl) * KTOT + 512 + kt * 16 + q * 8]);

  // gate cells: lane -> unit pair (up*2, up*2+1), rows rbase..rbase+3
  const int up = lane & 3;
  const int rbase = (lane >> 2) * 4;
  const int ug0 = cb * 8 + up * 2;
  float csv[4][2];
#pragma unroll
  for (int rr = 0; rr < 4; ++rr) {
    csv[rr][0] = cs_init[(rbase + rr) * NU + ug0];
    csv[rr][1] = cs_init[(rbase + rr) * NU + ug0 + 1];
  }

  __shared__ float zsh[4][64][33];

  for (int t = 0; t < T_STEPS; ++t) {
    // zx prefetch (C init), coalesced fragment-order loads — overlaps the poll
    const uint4* zp0 = reinterpret_cast<const uint4*>(
        &zxp[((((size_t)t * 64 + cb) * 2 + 0) * 64 + lane) * 16]);
    const uint4* zp1 = reinterpret_cast<const uint4*>(
        &zxp[((((size_t)t * 64 + cb) * 2 + 1) * 64 + lane) * 16]);
    const uint4 z00 = zp0[0], z01 = zp0[1];
    const uint4 z10 = zp1[0], z11 = zp1[1];

    if (t > 0) {
      const ull_t* fb = reinterpret_cast<const ull_t*>(flags + (size_t)(t - 1) * 8);
      int guard = 0;
      while (guard++ < (1 << 22)) {
        ull_t s0 = __hip_atomic_load(fb + 0, __ATOMIC_RELAXED, __HIP_MEMORY_SCOPE_AGENT);
        ull_t s1 = __hip_atomic_load(fb + 1, __ATOMIC_RELAXED, __HIP_MEMORY_SCOPE_AGENT);
        ull_t s2 = __hip_atomic_load(fb + 2, __ATOMIC_RELAXED, __HIP_MEMORY_SCOPE_AGENT);
        ull_t s3 = __hip_atomic_load(fb + 3, __ATOMIC_RELAXED, __HIP_MEMORY_SCOPE_AGENT);
        const unsigned tot = (unsigned)(s0 & 0xffffffffu) + (unsigned)(s0 >> 32) +
                             (unsigned)(s1 & 0xffffffffu) + (unsigned)(s1 >> 32) +
                             (unsigned)(s2 & 0xffffffffu) + (unsigned)(s2 >> 32) +
                             (unsigned)(s3 & 0xffffffffu) + (unsigned)(s3 >> 32);
        if (tot >= 64) break;
        __builtin_amdgcn_s_sleep(4);
      }
    }

    // acc init from zx
    floatx16 acc0, acc1;
    {
      const unsigned* pa = reinterpret_cast<const unsigned*>(&z00);
      const unsigned* pb = reinterpret_cast<const unsigned*>(&z01);
      const unsigned* pc = reinterpret_cast<const unsigned*>(&z10);
      const unsigned* pd = reinterpret_cast<const unsigned*>(&z11);
#pragma unroll
      for (int i = 0; i < 4; ++i) {
        acc0[2 * i] = bf2f((unsigned short)(pa[i] & 0xffffu));
        acc0[2 * i + 1] = bf2f((unsigned short)(pa[i] >> 16));
        acc0[8 + 2 * i] = bf2f((unsigned short)(pb[i] & 0xffffu));
        acc0[8 + 2 * i + 1] = bf2f((unsigned short)(pb[i] >> 16));
        acc1[2 * i] = bf2f((unsigned short)(pc[i] & 0xffffu));
        acc1[2 * i + 1] = bf2f((unsigned short)(pc[i] >> 16));
        acc1[8 + 2 * i] = bf2f((unsigned short)(pd[i] & 0xffffu));
        acc1[8 + 2 * i + 1] = bf2f((unsigned short)(pd[i] >> 16));
      }
    }

    // A: h_prev (slot t), agent-coherent loads; chunks of 8 kt, double-buffered
    const unsigned short* hp = hbf + (size_t)t * (NB * NU);
    const unsigned short* a0base = hp + rl * NU + q * 8;
    const unsigned short* a1base = hp + (32 + rl) * NU + q * 8;
    bf16x8 A0[8], A1[8], A0n[8], A1n[8];
#pragma unroll
    for (int kk = 0; kk < 8; ++kk) {
      A0[kk] = ld_agent16(a0base + kk * 16);
      A1[kk] = ld_agent16(a1base + kk * 16);
    }
#pragma unroll
    for (int ch = 0; ch < 4; ++ch) {
      if (ch < 3) {
#pragma unroll
        for (int kk = 0; kk < 8; ++kk) {
          A0n[kk] = ld_agent16(a0base + (ch + 1) * 128 + kk * 16);
          A1n[kk] = ld_agent16(a1base + (ch + 1) * 128 + kk * 16);
        }
      }
#pragma unroll
      for (int kk = 0; kk < 8; ++kk) {
        acc0 = __builtin_amdgcn_mfma_f32_32x32x16_bf16(A0[kk], Bf[ch * 8 + kk], acc0, 0, 0, 0);
        acc1 = __builtin_amdgcn_mfma_f32_32x32x16_bf16(A1[kk], Bf[ch * 8 + kk], acc1, 0, 0, 0);
      }
#pragma unroll
      for (int kk = 0; kk < 8; ++kk) { A0[kk] = A0n[kk]; A1[kk] = A1n[kk]; }
    }

    // z -> LDS (wave-private region; no barrier needed)
#pragma unroll
    for (int reg = 0; reg < 16; ++reg) {
      const int rowc = (reg & 3) + 4 * q + 8 * (reg >> 2);
      zsh[wid][rowc][rl] = acc0[reg];
      zsh[wid][32 + rowc][rl] = acc1[reg];
    }

    // gates: per lane 2 units x 4 rows
#pragma unroll
    for (int rr = 0; rr < 4; ++rr) {
      const int row = rbase + rr;
      const float4 za = *reinterpret_cast<const float4*>(&zsh[wid][row][up * 8]);
      const float4 zb = *reinterpret_cast<const float4*>(&zsh[wid][row][up * 8 + 4]);
      // (i, ci, f, o)
      const float i0 = sigmoidf_(za.x), ci0 = tanhf(za.y);
      const float f0 = sigmoidf_(za.z + 1.0f), o0 = sigmoidf_(za.w);
      const float i1 = sigmoidf_(zb.x), ci1 = tanhf(zb.y);
      const float f1 = sigmoidf_(zb.z + 1.0f), o1 = sigmoidf_(zb.w);
      csv[rr][0] = ci0 * i0 + csv[rr][0] * f0;
      csv[rr][1] = ci1 * i1 + csv[rr][1] * f1;
      const float h0v = tanhf(csv[rr][0]) * o0;
      const float h1v = tanhf(csv[rr][1]) * o1;

      *reinterpret_cast<float2*>(&out[((size_t)t * NB + row) * NU + ug0]) =
          make_float2(h0v, h1v);
      const unsigned hv = (unsigned)f2bf(h0v) | ((unsigned)f2bf(h1v) << 16);
      __hip_atomic_store(
          reinterpret_cast<unsigned*>(&hbf[(size_t)(t + 1) * (NB * NU) + row * NU + ug0]),
          hv, __ATOMIC_RELAXED, __HIP_MEMORY_SCOPE_AGENT);
      if (t == T_STEPS - 1) {
        *reinterpret_cast<float2*>(&out[HSEQ_ELEMS + row * NU + ug0]) =
            make_float2(csv[rr][0], csv[rr][1]);
        *reinterpret_cast<float2*>(&out[HSEQ_ELEMS + NB * NU + row * NU + ug0]) =
            make_float2(h0v, h1v);
      }
    }

    // release: drain h stores, then signal
    asm volatile("s_waitcnt vmcnt(0)" ::: "memory");
    if (lane == 0)
      __hip_atomic_fetch_add(&flags[(size_t)t * 8 + (cb & 7)], 1u, __ATOMIC_RELAXED,
                             __HIP_MEMORY_SCOPE_AGENT);
  }
}

// ---------------------------------------------------------------------------
extern "C" void kernel_launch(void* const* d_in, const int* in_sizes, int n_in,
                              void* d_out, int out_size, void* d_ws, size_t ws_size,
                              hipStream_t stream) {
  const float* x = (const float*)d_in[0];
  const float* cs0 = (const float*)d_in[1];
  const float* h0 = (const float*)d_in[2];
  const float* w = (const float*)d_in[3];
  const float* bias = (const float*)d_in[4];
  float* out = (float*)d_out;

  char* ws = (char*)d_ws;
  unsigned short* wT = (unsigned short*)(ws);
  unsigned short* zxp = (unsigned short*)(ws + (size_t)(4 << 20));
  unsigned short* hbf = (unsigned short*)(ws + (size_t)(132 << 20));
  unsigned int* flags = (unsigned int*)(ws + (size_t)(164 << 20) + (1 << 16));

  init_kernel<<<dim3(128), 256, 0, stream>>>(h0, hbf, flags);
  transpose_w_kernel<<<dim3(16, 32, 4), 256, 0, stream>>>(w, wT);
  gemm_zx_kernel<<<dim3(16, 256), 256, 0, stream>>>(x, wT, bias, zxp);
  lstm_rec_kernel<<<dim3(16), 256, 0, stream>>>(zxp, wT, cs0, out, hbf, flags);
}

// Round 3
// 10026.440 us; speedup vs baseline: 2.1265x; 1.0642x over previous
//
#include <hip/hip_runtime.h>

// ---------------------------------------------------------------------------
// BlockLSTM forward, MI355X (gfx950).  T=512, B=64, I=U=512.
// out = [h_seq (T,B,U) | final_cs (B,U) | final_h (B,U)] fp32
//
// z-columns permuted unit-major: col' = u*4 + g  (orig col = g*512 + u).
// zxp stored in MFMA 32x32 C-fragment order: [t][cb][rt][lane][reg] bf16.
//
// ws layout (~164.1 MB):
//   [0,   4MB)        wT   bf16 [2048 permuted cols][1024 k]
//   [4MB, 132MB)      zxp  bf16 [512][64][2][64][16]
//   [132MB, +32.06MB) hbf  bf16 [513 slots][64][512]  (slot t = h_{t-1})
//   [164MB+64KB, +16KB) epochs u32 [64 waves][64]  (one 256B line per wave)
// ---------------------------------------------------------------------------

#define T_STEPS 512
#define NB 64
#define NU 512
#define NI 512
#define KTOT 1024
#define ZCOLS 2048
#define HSEQ_ELEMS (T_STEPS * NB * NU)

typedef float    floatx4   __attribute__((ext_vector_type(4)));
typedef float    floatx16  __attribute__((ext_vector_type(16)));
typedef __bf16   bf16x8    __attribute__((ext_vector_type(8)));
typedef unsigned short ushortx8 __attribute__((ext_vector_type(8)));
typedef unsigned long long ull_t;

static __device__ __forceinline__ unsigned short f2bf(float f) {
  unsigned int u = __builtin_bit_cast(unsigned int, f);
  u += 0x7fffu + ((u >> 16) & 1u);  // RNE
  return (unsigned short)(u >> 16);
}
static __device__ __forceinline__ float bf2f(unsigned short h) {
  unsigned int u = ((unsigned int)h) << 16;
  return __builtin_bit_cast(float, u);
}
static __device__ __forceinline__ float sigmoidf_(float x) {
  return 1.0f / (1.0f + __expf(-x));
}
// stable fast tanh: t = exp(-2|x|); r = sign(x) * (1-t)/(1+t)
static __device__ __forceinline__ float fast_tanhf(float x) {
  const float ax = fabsf(x);
  const float t = __expf(-2.0f * ax);
  const float r = (1.0f - t) / (1.0f + t);
  return copysignf(r, x);
}
static __device__ __forceinline__ bf16x8 ldfrag(const unsigned short* p) {
  ushortx8 v = *reinterpret_cast<const ushortx8*>(p);
  return __builtin_bit_cast(bf16x8, v);
}
static __device__ __forceinline__ ull_t pack4bf(float a, float b, float c, float d) {
  return (ull_t)f2bf(a) | ((ull_t)f2bf(b) << 16) | ((ull_t)f2bf(c) << 32) |
         ((ull_t)f2bf(d) << 48);
}
// 16B fragment load bypassing L1/L2 (agent-coherent read from IF$).
static __device__ __forceinline__ bf16x8 ld_agent16(const unsigned short* p) {
  ull_t lo = __hip_atomic_load((const ull_t*)p, __ATOMIC_RELAXED, __HIP_MEMORY_SCOPE_AGENT);
  ull_t hi = __hip_atomic_load((const ull_t*)(p + 4), __ATOMIC_RELAXED, __HIP_MEMORY_SCOPE_AGENT);
  struct P { ull_t a, b; } s{lo, hi};
  return __builtin_bit_cast(bf16x8, s);
}

// ---------------------------------------------------------------------------
__global__ __launch_bounds__(256) void init_kernel(const float* __restrict__ h0,
                                                   unsigned short* __restrict__ hbf,
                                                   unsigned int* __restrict__ epochs) {
  const int i = blockIdx.x * 256 + threadIdx.x;
  if (i < 64 * 64) epochs[i] = 0;
  if (i < NB * NU) hbf[i] = f2bf(h0[i]);
}

// ---------------------------------------------------------------------------
// transpose + permute: wT[(u*4+g)][k] = bf16(w[k][g*512+u])
// ---------------------------------------------------------------------------
__global__ __launch_bounds__(256) void transpose_w_kernel(
    const float* __restrict__ w, unsigned short* __restrict__ wT) {
  __shared__ float tile[32][33];
  const int u0 = blockIdx.x * 32;
  const int k0 = blockIdx.y * 32;
  const int g = blockIdx.z;
  const int tx = threadIdx.x & 31, ty = threadIdx.x >> 5;
#pragma unroll
  for (int r = 0; r < 4; ++r) {
    const int k = ty + r * 8;
    tile[k][tx] = w[(size_t)(k0 + k) * ZCOLS + g * 512 + u0 + tx];
  }
  __syncthreads();
#pragma unroll
  for (int r = 0; r < 4; ++r) {
    const int u = ty + r * 8;
    wT[(size_t)((u0 + u) * 4 + g) * KTOT + k0 + tx] = f2bf(tile[tx][u]);
  }
}

// ---------------------------------------------------------------------------
// gemm: zxp = (x @ wx + b) in permuted cols, stored in 32x32 C-fragment order.
// ---------------------------------------------------------------------------
__global__ __launch_bounds__(256) void gemm_zx_kernel(
    const float* __restrict__ x, const unsigned short* __restrict__ wT,
    const float* __restrict__ bias, unsigned short* __restrict__ zxp) {
  __shared__ __align__(16) unsigned short As[128][32];
  __shared__ __align__(16) unsigned short Bs[128][32];
  const int m0 = blockIdx.y * 128;
  const int n0 = blockIdx.x * 128;
  const int tid = threadIdx.x;
  const int wid = tid >> 6, lane = tid & 63;
  const int quad = lane >> 4, nl = lane & 15;
  const int wm = (wid & 1) * 64, wn = (wid >> 1) * 64;
  const int srow = tid >> 3;
  const int skk = (tid & 7) * 4;

  floatx4 acc[4][4] = {};

  for (int kt = 0; kt < 16; ++kt) {
    const int k0 = kt * 32;
    __syncthreads();
#pragma unroll
    for (int r = 0; r < 4; ++r) {
      const int row = r * 32 + srow;
      const float4 v =
          *reinterpret_cast<const float4*>(&x[(size_t)(m0 + row) * NI + k0 + skk]);
      *reinterpret_cast<ull_t*>(&As[row][skk]) = pack4bf(v.x, v.y, v.z, v.w);
      *reinterpret_cast<ull_t*>(&Bs[row][skk]) =
          *reinterpret_cast<const ull_t*>(&wT[(size_t)(n0 + row) * KTOT + k0 + skk]);
    }
    __syncthreads();
    bf16x8 af[4], bfr[4];
#pragma unroll
    for (int i = 0; i < 4; ++i) {
      af[i] = ldfrag(&As[wm + i * 16 + nl][quad * 8]);
      bfr[i] = ldfrag(&Bs[wn + i * 16 + nl][quad * 8]);
    }
#pragma unroll
    for (int i = 0; i < 4; ++i)
#pragma unroll
      for (int j = 0; j < 4; ++j)
        acc[i][j] =
            __builtin_amdgcn_mfma_f32_16x16x32_bf16(af[i], bfr[j], acc[i][j], 0, 0, 0);
  }

  float bv[4];
#pragma unroll
  for (int j = 0; j < 4; ++j) {
    const int colp = n0 + wn + j * 16 + nl;
    bv[j] = bias[(colp & 3) * 512 + (colp >> 2)];
  }
#pragma unroll
  for (int i = 0; i < 4; ++i) {
    const int browb = wm + i * 16 + quad * 4;
    const int t = (m0 + browb) >> 6;
    const int rt = (browb >> 5) & 1;
    const int hi = (browb & 31) >> 3;
    const int qb = (browb >> 2) & 1;
#pragma unroll
    for (int j = 0; j < 4; ++j) {
      const int colp = n0 + wn + j * 16 + nl;
      const int cbl = colp >> 5;
      const int lanep = (colp & 31) + 32 * qb;
      const ull_t packed =
          pack4bf(acc[i][j][0] + bv[j], acc[i][j][1] + bv[j],
                  acc[i][j][2] + bv[j], acc[i][j][3] + bv[j]);
      *reinterpret_cast<ull_t*>(
          &zxp[((((size_t)t * 64 + cbl) * 2 + rt) * 64 + lanep) * 16 + hi * 4]) = packed;
    }
  }
}

// ---------------------------------------------------------------------------
// recurrence: 16 blocks x 256 thr (64 waves). Wave = 32 permuted z-cols
// (= 8 units) x all 64 batch rows. wh resident in VGPR fragments.
// Sync: per-wave monotonic epoch word on its own 256B line; wave 0 of each
// block polls all 64 lines (one per lane), one __syncthreads releases.
// ---------------------------------------------------------------------------
__global__ __launch_bounds__(256) void lstm_rec_kernel(
    const unsigned short* __restrict__ zxp, const unsigned short* __restrict__ wT,
    const float* __restrict__ cs_init, float* __restrict__ out,
    unsigned short* __restrict__ hbf, unsigned int* __restrict__ epochs) {
  const int wid = threadIdx.x >> 6, lane = threadIdx.x & 63;
  const int cb = blockIdx.x * 4 + wid;  // wave id 0..63; units [cb*8, +8)
  const int rl = lane & 31, q = lane >> 5;

  // resident B fragments: wh rows (k=512..1023), cols [cb*32, +32)
  bf16x8 Bf[32];
#pragma unroll
  for (int kt = 0; kt < 32; ++kt)
    Bf[kt] = ldfrag(&wT[(size_t)(cb * 32 + rl) * KTOT + 512 + kt * 16 + q * 8]);

  // gate mapping: lane = batch row, owns units [u0, u0+8)
  const int u0 = cb * 8;
  float csv[8];
#pragma unroll
  for (int j = 0; j < 8; ++j) csv[j] = cs_init[lane * NU + u0 + j];

  __shared__ float zsh[4][64][33];

  for (int t = 0; t < T_STEPS; ++t) {
    // zx prefetch (C init) — issued before the poll, overlaps detection
    const uint4* zp0 = reinterpret_cast<const uint4*>(
        &zxp[((((size_t)t * 64 + cb) * 2 + 0) * 64 + lane) * 16]);
    const uint4* zp1 = reinterpret_cast<const uint4*>(
        &zxp[((((size_t)t * 64 + cb) * 2 + 1) * 64 + lane) * 16]);
    const uint4 z00 = zp0[0], z01 = zp0[1];
    const uint4 z10 = zp1[0], z11 = zp1[1];

    // wave 0 polls: lane i watches producer-wave i's epoch (64 distinct lines)
    if (wid == 0 && t > 0) {
      const unsigned int* ep = &epochs[lane * 64];
      int guard = 0;
      while (guard++ < (1 << 22)) {
        const unsigned e =
            __hip_atomic_load(ep, __ATOMIC_RELAXED, __HIP_MEMORY_SCOPE_AGENT);
        if (__all((int)(e >= (unsigned)t))) break;
        __builtin_amdgcn_s_sleep(1);
      }
    }
    __syncthreads();  // release: h slot t visible to all waves

    // acc init from zx
    floatx16 acc0, acc1;
    {
      const unsigned* pa = reinterpret_cast<const unsigned*>(&z00);
      const unsigned* pb = reinterpret_cast<const unsigned*>(&z01);
      const unsigned* pc = reinterpret_cast<const unsigned*>(&z10);
      const unsigned* pd = reinterpret_cast<const unsigned*>(&z11);
#pragma unroll
      for (int i = 0; i < 4; ++i) {
        acc0[2 * i] = bf2f((unsigned short)(pa[i] & 0xffffu));
        acc0[2 * i + 1] = bf2f((unsigned short)(pa[i] >> 16));
        acc0[8 + 2 * i] = bf2f((unsigned short)(pb[i] & 0xffffu));
        acc0[8 + 2 * i + 1] = bf2f((unsigned short)(pb[i] >> 16));
        acc1[2 * i] = bf2f((unsigned short)(pc[i] & 0xffffu));
        acc1[2 * i + 1] = bf2f((unsigned short)(pc[i] >> 16));
        acc1[8 + 2 * i] = bf2f((unsigned short)(pd[i] & 0xffffu));
        acc1[8 + 2 * i + 1] = bf2f((unsigned short)(pd[i] >> 16));
      }
    }

    // A: h_prev (slot t), agent loads; chunks of 8 kt, double-buffered
    const unsigned short* hp = hbf + (size_t)t * (NB * NU);
    const unsigned short* a0base = hp + rl * NU + q * 8;
    const unsigned short* a1base = hp + (32 + rl) * NU + q * 8;
    bf16x8 A0[8], A1[8], A0n[8], A1n[8];
#pragma unroll
    for (int kk = 0; kk < 8; ++kk) {
      A0[kk] = ld_agent16(a0base + kk * 16);
      A1[kk] = ld_agent16(a1base + kk * 16);
    }
#pragma unroll
    for (int ch = 0; ch < 4; ++ch) {
      if (ch < 3) {
#pragma unroll
        for (int kk = 0; kk < 8; ++kk) {
          A0n[kk] = ld_agent16(a0base + (ch + 1) * 128 + kk * 16);
          A1n[kk] = ld_agent16(a1base + (ch + 1) * 128 + kk * 16);
        }
      }
#pragma unroll
      for (int kk = 0; kk < 8; ++kk) {
        acc0 = __builtin_amdgcn_mfma_f32_32x32x16_bf16(A0[kk], Bf[ch * 8 + kk], acc0, 0, 0, 0);
        acc1 = __builtin_amdgcn_mfma_f32_32x32x16_bf16(A1[kk], Bf[ch * 8 + kk], acc1, 0, 0, 0);
      }
#pragma unroll
      for (int kk = 0; kk < 8; ++kk) { A0[kk] = A0n[kk]; A1[kk] = A1n[kk]; }
    }

    // z -> LDS (wave-private region; no barrier needed)
#pragma unroll
    for (int reg = 0; reg < 16; ++reg) {
      const int rowc = (reg & 3) + 4 * q + 8 * (reg >> 2);
      zsh[wid][rowc][rl] = acc0[reg];
      zsh[wid][32 + rowc][rl] = acc1[reg];
    }

    // gates: lane = row, 8 units; z cols (u*4 .. u*4+3) = (i, ci, f, o)
    float hout[8];
#pragma unroll
    for (int u = 0; u < 8; ++u) {
      const float4 zg = *reinterpret_cast<const float4*>(&zsh[wid][lane][u * 4]);
      const float iv = sigmoidf_(zg.x);
      const float civ = fast_tanhf(zg.y);
      const float fv = sigmoidf_(zg.z + 1.0f);  // forget_bias
      const float ov = sigmoidf_(zg.w);
      csv[u] = civ * iv + csv[u] * fv;
      hout[u] = fast_tanhf(csv[u]) * ov;
    }

    // h broadcast: 2x8B write-through stores, then drain ONLY these + signal
    unsigned short* hw = &hbf[(size_t)(t + 1) * (NB * NU) + lane * NU + u0];
    __hip_atomic_store(reinterpret_cast<ull_t*>(hw),
                       pack4bf(hout[0], hout[1], hout[2], hout[3]),
                       __ATOMIC_RELAXED, __HIP_MEMORY_SCOPE_AGENT);
    __hip_atomic_store(reinterpret_cast<ull_t*>(hw + 4),
                       pack4bf(hout[4], hout[5], hout[6], hout[7]),
                       __ATOMIC_RELAXED, __HIP_MEMORY_SCOPE_AGENT);
    asm volatile("s_waitcnt vmcnt(0)" ::: "memory");
    if (lane == 0)
      __hip_atomic_store(&epochs[cb * 64], (unsigned)(t + 1), __ATOMIC_RELAXED,
                         __HIP_MEMORY_SCOPE_AGENT);

    // out stores AFTER the signal (not on the critical path)
    float* op = &out[((size_t)t * NB + lane) * NU + u0];
    *reinterpret_cast<float4*>(op) = make_float4(hout[0], hout[1], hout[2], hout[3]);
    *reinterpret_cast<float4*>(op + 4) = make_float4(hout[4], hout[5], hout[6], hout[7]);
    if (t == T_STEPS - 1) {
      float* cp = &out[HSEQ_ELEMS + lane * NU + u0];
      *reinterpret_cast<float4*>(cp) = make_float4(csv[0], csv[1], csv[2], csv[3]);
      *reinterpret_cast<float4*>(cp + 4) = make_float4(csv[4], csv[5], csv[6], csv[7]);
      float* hp2 = &out[HSEQ_ELEMS + NB * NU + lane * NU + u0];
      *reinterpret_cast<float4*>(hp2) = make_float4(hout[0], hout[1], hout[2], hout[3]);
      *reinterpret_cast<float4*>(hp2 + 4) = make_float4(hout[4], hout[5], hout[6], hout[7]);
    }
  }
}

// ---------------------------------------------------------------------------
extern "C" void kernel_launch(void* const* d_in, const int* in_sizes, int n_in,
                              void* d_out, int out_size, void* d_ws, size_t ws_size,
                              hipStream_t stream) {
  const float* x = (const float*)d_in[0];
  const float* cs0 = (const float*)d_in[1];
  const float* h0 = (const float*)d_in[2];
  const float* w = (const float*)d_in[3];
  const float* bias = (const float*)d_in[4];
  float* out = (float*)d_out;

  char* ws = (char*)d_ws;
  unsigned short* wT = (unsigned short*)(ws);
  unsigned short* zxp = (unsigned short*)(ws + (size_t)(4 << 20));
  unsigned short* hbf = (unsigned short*)(ws + (size_t)(132 << 20));
  unsigned int* epochs = (unsigned int*)(ws + (size_t)(164 << 20) + (1 << 16));

  init_kernel<<<dim3(128), 256, 0, stream>>>(h0, hbf, epochs);
  transpose_w_kernel<<<dim3(16, 32, 4), 256, 0, stream>>>(w, wT);
  gemm_zx_kernel<<<dim3(16, 256), 256, 0, stream>>>(x, wT, bias, zxp);
  lstm_rec_kernel<<<dim3(16), 256, 0, stream>>>(zxp, wT, cs0, out, hbf, epochs);
}

// Round 4
// 4429.531 us; speedup vs baseline: 4.8134x; 2.2635x over previous
//
#include <hip/hip_runtime.h>

// ---------------------------------------------------------------------------
// BlockLSTM forward, MI355X (gfx950).  T=512, B=64, I=U=512.
// out = [h_seq (T,B,U) | final_cs (B,U) | final_h (B,U)] fp32
//
// z-columns permuted unit-major: col' = u*4 + g  (orig col = g*512 + u).
// zxp stored in MFMA 32x32 C-fragment order: [t][cb][rt][lane][reg] bf16.
// hbf stored in MFMA 32x32 A-fragment order:
//   elem offset(t, row, unit) = t*32768 + (row>>5)*16384 + (unit>>3)*256
//                               + (row&31)*8 + (unit&7)
//   -> producer wave cb writes two dense 512B segments; consumer loads are
//      fully-coalesced 1KB per instruction (kt*512 + lane*8).
//
// ws layout (~164.1 MB):
//   [0,   4MB)        wT   bf16 [2048 permuted cols][1024 k]
//   [4MB, 132MB)      zxp  bf16 [512][64][2][64][16]
//   [132MB, +32.06MB) hbf  bf16 [513 slots][32768]  (slot t = h_{t-1}, frag order)
//   [164MB+64KB, +16KB) epochs u32 [64 waves][64]  (one 256B line per wave)
// ---------------------------------------------------------------------------

#define T_STEPS 512
#define NB 64
#define NU 512
#define NI 512
#define KTOT 1024
#define ZCOLS 2048
#define HSEQ_ELEMS (T_STEPS * NB * NU)

typedef float    floatx4   __attribute__((ext_vector_type(4)));
typedef float    floatx16  __attribute__((ext_vector_type(16)));
typedef __bf16   bf16x8    __attribute__((ext_vector_type(8)));
typedef unsigned short ushortx8 __attribute__((ext_vector_type(8)));
typedef unsigned long long ull_t;

static __device__ __forceinline__ unsigned short f2bf(float f) {
  unsigned int u = __builtin_bit_cast(unsigned int, f);
  u += 0x7fffu + ((u >> 16) & 1u);  // RNE
  return (unsigned short)(u >> 16);
}
static __device__ __forceinline__ float bf2f(unsigned short h) {
  unsigned int u = ((unsigned int)h) << 16;
  return __builtin_bit_cast(float, u);
}
static __device__ __forceinline__ float sigmoidf_(float x) {
  return 1.0f / (1.0f + __expf(-x));
}
// stable fast tanh: t = exp(-2|x|); r = sign(x) * (1-t)/(1+t)
static __device__ __forceinline__ float fast_tanhf(float x) {
  const float ax = fabsf(x);
  const float t = __expf(-2.0f * ax);
  const float r = (1.0f - t) / (1.0f + t);
  return copysignf(r, x);
}
static __device__ __forceinline__ bf16x8 ldfrag(const unsigned short* p) {
  ushortx8 v = *reinterpret_cast<const ushortx8*>(p);
  return __builtin_bit_cast(bf16x8, v);
}
static __device__ __forceinline__ ull_t pack4bf(float a, float b, float c, float d) {
  return (ull_t)f2bf(a) | ((ull_t)f2bf(b) << 16) | ((ull_t)f2bf(c) << 32) |
         ((ull_t)f2bf(d) << 48);
}
// 16B fragment load bypassing L1/L2 (agent-coherent read from IF$).
static __device__ __forceinline__ bf16x8 ld_agent16(const unsigned short* p) {
  ull_t lo = __hip_atomic_load((const ull_t*)p, __ATOMIC_RELAXED, __HIP_MEMORY_SCOPE_AGENT);
  ull_t hi = __hip_atomic_load((const ull_t*)(p + 4), __ATOMIC_RELAXED, __HIP_MEMORY_SCOPE_AGENT);
  struct P { ull_t a, b; } s{lo, hi};
  return __builtin_bit_cast(bf16x8, s);
}

// ---------------------------------------------------------------------------
// init: zero epochs; hbf slot0 = bf16(h0) in A-fragment order.  grid 16x256.
// ---------------------------------------------------------------------------
__global__ __launch_bounds__(256) void init_kernel(const float* __restrict__ h0,
                                                   unsigned short* __restrict__ hbf,
                                                   unsigned int* __restrict__ epochs) {
  const int i = blockIdx.x * 256 + threadIdx.x;  // 0..4095
  epochs[i] = 0;
  const int row = i >> 6, chunk = i & 63;        // chunk = unit>>3
  const float* src = &h0[row * NU + chunk * 8];
  const ull_t lo = pack4bf(src[0], src[1], src[2], src[3]);
  const ull_t hi = pack4bf(src[4], src[5], src[6], src[7]);
  const size_t off = ((size_t)((row >> 5) * 64 + chunk) * 32 + (row & 31)) * 8;
  *reinterpret_cast<ull_t*>(&hbf[off]) = lo;
  *reinterpret_cast<ull_t*>(&hbf[off + 4]) = hi;
}

// ---------------------------------------------------------------------------
// transpose + permute: wT[(u*4+g)][k] = bf16(w[k][g*512+u])
// ---------------------------------------------------------------------------
__global__ __launch_bounds__(256) void transpose_w_kernel(
    const float* __restrict__ w, unsigned short* __restrict__ wT) {
  __shared__ float tile[32][33];
  const int u0 = blockIdx.x * 32;
  const int k0 = blockIdx.y * 32;
  const int g = blockIdx.z;
  const int tx = threadIdx.x & 31, ty = threadIdx.x >> 5;
#pragma unroll
  for (int r = 0; r < 4; ++r) {
    const int k = ty + r * 8;
    tile[k][tx] = w[(size_t)(k0 + k) * ZCOLS + g * 512 + u0 + tx];
  }
  __syncthreads();
#pragma unroll
  for (int r = 0; r < 4; ++r) {
    const int u = ty + r * 8;
    wT[(size_t)((u0 + u) * 4 + g) * KTOT + k0 + tx] = f2bf(tile[tx][u]);
  }
}

// ---------------------------------------------------------------------------
// gemm: zxp = (x @ wx + b) in permuted cols, stored in 32x32 C-fragment order.
// ---------------------------------------------------------------------------
__global__ __launch_bounds__(256) void gemm_zx_kernel(
    const float* __restrict__ x, const unsigned short* __restrict__ wT,
    const float* __restrict__ bias, unsigned short* __restrict__ zxp) {
  __shared__ __align__(16) unsigned short As[128][32];
  __shared__ __align__(16) unsigned short Bs[128][32];
  const int m0 = blockIdx.y * 128;
  const int n0 = blockIdx.x * 128;
  const int tid = threadIdx.x;
  const int wid = tid >> 6, lane = tid & 63;
  const int quad = lane >> 4, nl = lane & 15;
  const int wm = (wid & 1) * 64, wn = (wid >> 1) * 64;
  const int srow = tid >> 3;
  const int skk = (tid & 7) * 4;

  floatx4 acc[4][4] = {};

  for (int kt = 0; kt < 16; ++kt) {
    const int k0 = kt * 32;
    __syncthreads();
#pragma unroll
    for (int r = 0; r < 4; ++r) {
      const int row = r * 32 + srow;
      const float4 v =
          *reinterpret_cast<const float4*>(&x[(size_t)(m0 + row) * NI + k0 + skk]);
      *reinterpret_cast<ull_t*>(&As[row][skk]) = pack4bf(v.x, v.y, v.z, v.w);
      *reinterpret_cast<ull_t*>(&Bs[row][skk]) =
          *reinterpret_cast<const ull_t*>(&wT[(size_t)(n0 + row) * KTOT + k0 + skk]);
    }
    __syncthreads();
    bf16x8 af[4], bfr[4];
#pragma unroll
    for (int i = 0; i < 4; ++i) {
      af[i] = ldfrag(&As[wm + i * 16 + nl][quad * 8]);
      bfr[i] = ldfrag(&Bs[wn + i * 16 + nl][quad * 8]);
    }
#pragma unroll
    for (int i = 0; i < 4; ++i)
#pragma unroll
      for (int j = 0; j < 4; ++j)
        acc[i][j] =
            __builtin_amdgcn_mfma_f32_16x16x32_bf16(af[i], bfr[j], acc[i][j], 0, 0, 0);
  }

  float bv[4];
#pragma unroll
  for (int j = 0; j < 4; ++j) {
    const int colp = n0 + wn + j * 16 + nl;
    bv[j] = bias[(colp & 3) * 512 + (colp >> 2)];
  }
#pragma unroll
  for (int i = 0; i < 4; ++i) {
    const int browb = wm + i * 16 + quad * 4;
    const int t = (m0 + browb) >> 6;
    const int rt = (browb >> 5) & 1;
    const int hi = (browb & 31) >> 3;
    const int qb = (browb >> 2) & 1;
#pragma unroll
    for (int j = 0; j < 4; ++j) {
      const int colp = n0 + wn + j * 16 + nl;
      const int cbl = colp >> 5;
      const int lanep = (colp & 31) + 32 * qb;
      const ull_t packed =
          pack4bf(acc[i][j][0] + bv[j], acc[i][j][1] + bv[j],
                  acc[i][j][2] + bv[j], acc[i][j][3] + bv[j]);
      *reinterpret_cast<ull_t*>(
          &zxp[((((size_t)t * 64 + cbl) * 2 + rt) * 64 + lanep) * 16 + hi * 4]) = packed;
    }
  }
}

// ---------------------------------------------------------------------------
// recurrence: 64 blocks x 64 thr (1 wave each). Wave cb = units [cb*8, +8)
// x all 64 batch rows. wh resident in VGPR fragments. No __syncthreads at all.
// Sync: per-wave monotonic epoch on its own 256B line; every wave polls all
// 64 lines (one per lane) with __all.
// ---------------------------------------------------------------------------
__global__ __launch_bounds__(64) void lstm_rec_kernel(
    const unsigned short* __restrict__ zxp, const unsigned short* __restrict__ wT,
    const float* __restrict__ cs_init, float* __restrict__ out,
    unsigned short* __restrict__ hbf, unsigned int* __restrict__ epochs) {
  const int lane = threadIdx.x;
  const int cb = blockIdx.x;             // 0..63; units [cb*8, +8)
  const int rl = lane & 31, q = lane >> 5;

  // resident B fragments: wh rows (k=512..1023), cols [cb*32, +32)
  bf16x8 Bf[32];
#pragma unroll
  for (int kt = 0; kt < 32; ++kt)
    Bf[kt] = ldfrag(&wT[(size_t)(cb * 32 + rl) * KTOT + 512 + kt * 16 + q * 8]);

  // gate mapping: lane = batch row, owns units [u0, u0+8)
  const int u0 = cb * 8;
  float csv[8];
#pragma unroll
  for (int j = 0; j < 8; ++j) csv[j] = cs_init[lane * NU + u0 + j];

  __shared__ float zsh[64][33];

  for (int t = 0; t < T_STEPS; ++t) {
    // zx prefetch (C init) — issued before the poll, overlaps detection
    const uint4* zp0 = reinterpret_cast<const uint4*>(
        &zxp[((((size_t)t * 64 + cb) * 2 + 0) * 64 + lane) * 16]);
    const uint4* zp1 = reinterpret_cast<const uint4*>(
        &zxp[((((size_t)t * 64 + cb) * 2 + 1) * 64 + lane) * 16]);
    const uint4 z00 = zp0[0], z01 = zp0[1];
    const uint4 z10 = zp1[0], z11 = zp1[1];

    // poll: lane i watches producer-wave i's epoch (64 distinct 256B lines)
    if (t > 0) {
      const unsigned int* ep = &epochs[lane * 64];
      int guard = 0;
      while (guard++ < (1 << 20)) {
        const unsigned e =
            __hip_atomic_load(ep, __ATOMIC_RELAXED, __HIP_MEMORY_SCOPE_AGENT);
        if (__all((int)(e >= (unsigned)t))) break;
        __builtin_amdgcn_s_sleep(1);
      }
    }

    // acc init from zx
    floatx16 acc0, acc1;
    {
      const unsigned* pa = reinterpret_cast<const unsigned*>(&z00);
      const unsigned* pb = reinterpret_cast<const unsigned*>(&z01);
      const unsigned* pc = reinterpret_cast<const unsigned*>(&z10);
      const unsigned* pd = reinterpret_cast<const unsigned*>(&z11);
#pragma unroll
      for (int i = 0; i < 4; ++i) {
        acc0[2 * i] = bf2f((unsigned short)(pa[i] & 0xffffu));
        acc0[2 * i + 1] = bf2f((unsigned short)(pa[i] >> 16));
        acc0[8 + 2 * i] = bf2f((unsigned short)(pb[i] & 0xffffu));
        acc0[8 + 2 * i + 1] = bf2f((unsigned short)(pb[i] >> 16));
        acc1[2 * i] = bf2f((unsigned short)(pc[i] & 0xffffu));
        acc1[2 * i + 1] = bf2f((unsigned short)(pc[i] >> 16));
        acc1[8 + 2 * i] = bf2f((unsigned short)(pd[i] & 0xffffu));
        acc1[8 + 2 * i + 1] = bf2f((unsigned short)(pd[i] >> 16));
      }
    }

    // A: h_prev (slot t) in fragment order — every load is a dense 1KB/wave.
    // A0[kt] = rows 0..31 frag, A1[kt] = rows 32..63 frag (j*16384 offset).
    const unsigned short* hp = hbf + (size_t)t * (NB * NU) + lane * 8;
    bf16x8 A0[8], A1[8], A0n[8], A1n[8];
#pragma unroll
    for (int kk = 0; kk < 8; ++kk) {
      A0[kk] = ld_agent16(hp + kk * 512);
      A1[kk] = ld_agent16(hp + 16384 + kk * 512);
    }
#pragma unroll
    for (int ch = 0; ch < 4; ++ch) {
      if (ch < 3) {
#pragma unroll
        for (int kk = 0; kk < 8; ++kk) {
          A0n[kk] = ld_agent16(hp + (ch + 1) * 4096 + kk * 512);
          A1n[kk] = ld_agent16(hp + 16384 + (ch + 1) * 4096 + kk * 512);
        }
      }
#pragma unroll
      for (int kk = 0; kk < 8; ++kk) {
        acc0 = __builtin_amdgcn_mfma_f32_32x32x16_bf16(A0[kk], Bf[ch * 8 + kk], acc0, 0, 0, 0);
        acc1 = __builtin_amdgcn_mfma_f32_32x32x16_bf16(A1[kk], Bf[ch * 8 + kk], acc1, 0, 0, 0);
      }
#pragma unroll
      for (int kk = 0; kk < 8; ++kk) { A0[kk] = A0n[kk]; A1[kk] = A1n[kk]; }
    }

    // z -> LDS (single wave, no barrier)
#pragma unroll
    for (int reg = 0; reg < 16; ++reg) {
      const int rowc = (reg & 3) + 4 * q + 8 * (reg >> 2);
      zsh[rowc][rl] = acc0[reg];
      zsh[32 + rowc][rl] = acc1[reg];
    }

    // gates: lane = row, 8 units; z cols (u*4 .. u*4+3) = (i, ci, f, o)
    float hout[8];
#pragma unroll
    for (int u = 0; u < 8; ++u) {
      const float4 zg = *reinterpret_cast<const float4*>(&zsh[lane][u * 4]);
      const float iv = sigmoidf_(zg.x);
      const float civ = fast_tanhf(zg.y);
      const float fv = sigmoidf_(zg.z + 1.0f);  // forget_bias
      const float ov = sigmoidf_(zg.w);
      csv[u] = civ * iv + csv[u] * fv;
      hout[u] = fast_tanhf(csv[u]) * ov;
    }

    // h broadcast in A-fragment order: two dense 512B segments per wave.
    unsigned short* hw = &hbf[(size_t)(t + 1) * (NB * NU) +
                              (size_t)(lane >> 5) * 16384 + cb * 256 + (lane & 31) * 8];
    __hip_atomic_store(reinterpret_cast<ull_t*>(hw),
                       pack4bf(hout[0], hout[1], hout[2], hout[3]),
                       __ATOMIC_RELAXED, __HIP_MEMORY_SCOPE_AGENT);
    __hip_atomic_store(reinterpret_cast<ull_t*>(hw + 4),
                       pack4bf(hout[4], hout[5], hout[6], hout[7]),
                       __ATOMIC_RELAXED, __HIP_MEMORY_SCOPE_AGENT);
    asm volatile("s_waitcnt vmcnt(0)" ::: "memory");
    if (lane == 0)
      __hip_atomic_store(&epochs[cb * 64], (unsigned)(t + 1), __ATOMIC_RELAXED,
                         __HIP_MEMORY_SCOPE_AGENT);

    // out stores AFTER the signal (not on the critical path)
    float* op = &out[((size_t)t * NB + lane) * NU + u0];
    *reinterpret_cast<float4*>(op) = make_float4(hout[0], hout[1], hout[2], hout[3]);
    *reinterpret_cast<float4*>(op + 4) = make_float4(hout[4], hout[5], hout[6], hout[7]);
    if (t == T_STEPS - 1) {
      float* cp = &out[HSEQ_ELEMS + lane * NU + u0];
      *reinterpret_cast<float4*>(cp) = make_float4(csv[0], csv[1], csv[2], csv[3]);
      *reinterpret_cast<float4*>(cp + 4) = make_float4(csv[4], csv[5], csv[6], csv[7]);
      float* hp2 = &out[HSEQ_ELEMS + NB * NU + lane * NU + u0];
      *reinterpret_cast<float4*>(hp2) = make_float4(hout[0], hout[1], hout[2], hout[3]);
      *reinterpret_cast<float4*>(hp2 + 4) = make_float4(hout[4], hout[5], hout[6], hout[7]);
    }
  }
}

// ---------------------------------------------------------------------------
extern "C" void kernel_launch(void* const* d_in, const int* in_sizes, int n_in,
                              void* d_out, int out_size, void* d_ws, size_t ws_size,
                              hipStream_t stream) {
  const float* x = (const float*)d_in[0];
  const float* cs0 = (const float*)d_in[1];
  const float* h0 = (const float*)d_in[2];
  const float* w = (const float*)d_in[3];
  const float* bias = (const float*)d_in[4];
  float* out = (float*)d_out;

  char* ws = (char*)d_ws;
  unsigned short* wT = (unsigned short*)(ws);
  unsigned short* zxp = (unsigned short*)(ws + (size_t)(4 << 20));
  unsigned short* hbf = (unsigned short*)(ws + (size_t)(132 << 20));
  unsigned int* epochs = (unsigned int*)(ws + (size_t)(164 << 20) + (1 << 16));

  init_kernel<<<dim3(16), 256, 0, stream>>>(h0, hbf, epochs);
  transpose_w_kernel<<<dim3(16, 32, 4), 256, 0, stream>>>(w, wT);
  gemm_zx_kernel<<<dim3(16, 256), 256, 0, stream>>>(x, wT, bias, zxp);
  lstm_rec_kernel<<<dim3(64), 64, 0, stream>>>(zxp, wT, cs0, out, hbf, epochs);
}